// Round 1
// baseline (427.398 us; speedup 1.0000x reference)
//
#include <hip/hip_runtime.h>

typedef _Float16 f16;
typedef f16 half8 __attribute__((ext_vector_type(8)));
typedef f16 f16x4 __attribute__((ext_vector_type(4)));
typedef float f32x4 __attribute__((ext_vector_type(4)));

#define GLOAD_LDS16(gsrc, ldst)                                                              \
  __builtin_amdgcn_global_load_lds((const __attribute__((address_space(1))) void*)(gsrc),    \
                                   (__attribute__((address_space(3))) void*)(ldst), 16, 0, 0)

constexpr float SCALE = 0.125f;  // 64^-0.5

// ---------------- convert f32 -> f16, vectorized x4 ----------------
__global__ __launch_bounds__(256) void k_cvt(const float4* __restrict__ in,
                                             f16x4* __restrict__ out, int n4) {
  int i = blockIdx.x * 256 + threadIdx.x;
  if (i < n4) {
    float4 v = in[i];
    f16x4 o;
    o[0] = (f16)v.x; o[1] = (f16)v.y; o[2] = (f16)v.z; o[3] = (f16)v.w;
    out[i] = o;
  }
}

// ---------------- transpose f32 [R][C] -> f16 [C][R] ----------------
__global__ __launch_bounds__(256) void k_transpose(const float* __restrict__ in,
                                                   f16* __restrict__ out, int R, int C) {
  __shared__ float t[32][33];
  int c0 = blockIdx.x * 32, r0 = blockIdx.y * 32;
  int tx = threadIdx.x, ty = threadIdx.y;
  for (int i = ty; i < 32; i += 8) t[i][tx] = in[(size_t)(r0 + i) * C + c0 + tx];
  __syncthreads();
  for (int i = ty; i < 32; i += 8) out[(size_t)(c0 + i) * R + r0 + tx] = (f16)t[tx][i];
}

// ---------------- GEMM: C[M][N] = A[M][1024] * Bt[N][1024]^T ----------------
// 128x128 tile, BK=64, 4 waves (2x2), each wave 64x64 via 4x4 16x16x32 MFMA frags.
// LDS tiles XOR-swizzled (slot ^= row&7) with pre-swizzled global source so the
// linear global_load_lds destination matches (both-sides-or-neither, rule #21).
// MODE 0: scatter epilogue into Q (pre-scaled), K, V^T per e = d*48 + which*16 + h.
// MODE 1: plain fp32 store (N=1024).
template <int MODE>
__global__ __launch_bounds__(256) void k_gemm(const f16* __restrict__ A,
                                              const f16* __restrict__ Bt,
                                              float* __restrict__ C,
                                              f16* __restrict__ Qp,
                                              f16* __restrict__ Kp,
                                              f16* __restrict__ Vt) {
  constexpr int K = 1024, BK = 64;
  __shared__ alignas(16) f16 As[128 * BK];
  __shared__ alignas(16) f16 Bs[128 * BK];
  const int tid = threadIdx.x;
  const int w = tid >> 6, lane = tid & 63;
  const int g = lane >> 4, lr = lane & 15;
  const int wr = w >> 1, wc = w & 1;
  const int m0 = blockIdx.y * 128, n0 = blockIdx.x * 128;
  const int srow = lane >> 3;                 // row within 8-row chunk
  const int scol = ((lane & 7) ^ srow) << 3;  // swizzled half offset within 64-half row

  f32x4 acc[4][4] = {};

  for (int kt = 0; kt < K; kt += BK) {
    __syncthreads();
#pragma unroll
    for (int i = 0; i < 4; ++i) {
      const int chunk = w * 4 + i;
      const int row = chunk * 8 + srow;
      GLOAD_LDS16(A + (size_t)(m0 + row) * K + kt + scol, &As[chunk * 512]);
      GLOAD_LDS16(Bt + (size_t)(n0 + row) * K + kt + scol, &Bs[chunk * 512]);
    }
    __syncthreads();
#pragma unroll
    for (int c = 0; c < 2; ++c) {
      half8 af[4], bf[4];
#pragma unroll
      for (int m = 0; m < 4; ++m) {
        const int ra = wr * 64 + m * 16 + lr;
        const int off = ra * 128 + ((((c << 2) | g) ^ (ra & 7)) << 4);
        af[m] = *(const half8*)((const char*)As + off);
      }
#pragma unroll
      for (int n = 0; n < 4; ++n) {
        const int rb = wc * 64 + n * 16 + lr;
        const int off = rb * 128 + ((((c << 2) | g) ^ (rb & 7)) << 4);
        bf[n] = *(const half8*)((const char*)Bs + off);
      }
#pragma unroll
      for (int m = 0; m < 4; ++m)
#pragma unroll
        for (int n = 0; n < 4; ++n)
          acc[m][n] = __builtin_amdgcn_mfma_f32_16x16x32_f16(af[m], bf[n], acc[m][n], 0, 0, 0);
    }
  }

  // D layout (m89-verified): col = lane&15, row = 4*(lane>>4) + reg
  if constexpr (MODE == 0) {
#pragma unroll
    for (int m = 0; m < 4; ++m) {
      const int trow = m0 + wr * 64 + m * 16 + 4 * g;
#pragma unroll
      for (int n = 0; n < 4; ++n) {
        const int e = n0 + wc * 64 + n * 16 + lr;  // e = d*48 + wh*16 + h
        const int d = e / 48;
        const int rem = e - d * 48;
        const int wh = rem >> 4, h = rem & 15;
#pragma unroll
        for (int r = 0; r < 4; ++r) {
          const int tok = trow + r;
          const int bh = ((tok >> 11) << 4) + h;
          const int nn = tok & 2047;
          const float v = acc[m][n][r];
          if (wh == 0)
            Qp[((size_t)bh * 2048 + nn) * 64 + d] = (f16)(v * SCALE);
          else if (wh == 1)
            Kp[((size_t)bh * 2048 + nn) * 64 + d] = (f16)v;
          else
            Vt[((size_t)bh * 64 + d) * 2048 + nn] = (f16)v;
        }
      }
    }
  } else {
#pragma unroll
    for (int m = 0; m < 4; ++m)
#pragma unroll
      for (int n = 0; n < 4; ++n)
#pragma unroll
        for (int r = 0; r < 4; ++r)
          C[(size_t)(m0 + wr * 64 + m * 16 + 4 * g + r) * 1024 +
            (n0 + wc * 64 + n * 16 + lr)] = acc[m][n][r];
  }
}

// ---------------- causal flash attention ----------------
// 4 independent waves per block (NO barriers: causal trip counts diverge per wave).
// Per wave: 16 q-rows, KV tiles of 64, online softmax, P transposed via padded
// wave-private LDS ([16][72] breaks the 8-way bank conflict).
__global__ __launch_bounds__(256) void k_attn(const f16* __restrict__ Q,
                                              const f16* __restrict__ Kp,
                                              const f16* __restrict__ Vt,
                                              f16* __restrict__ O) {
  __shared__ alignas(16) f16 plds_all[4][16][72];
  const int tid = threadIdx.x;
  const int w = tid >> 6, lane = tid & 63;
  const int g = lane >> 4, lr = lane & 15;
  const int bh = blockIdx.x >> 5;
  const int q0 = (blockIdx.x & 31) * 64 + w * 16;
  f16(*plds)[72] = plds_all[w];

  const f16* __restrict__ Qb = Q + (size_t)bh * (2048 * 64);
  const f16* __restrict__ Kb = Kp + (size_t)bh * (2048 * 64);
  const f16* __restrict__ Vb = Vt + (size_t)bh * (64 * 2048);

  // Q fragments: A-layout row = lane&15, k = 8*(lane>>4)+i (contiguous 8)
  const half8 qf0 = *(const half8*)(Qb + (size_t)(q0 + lr) * 64 + 8 * g);
  const half8 qf1 = *(const half8*)(Qb + (size_t)(q0 + lr) * 64 + 32 + 8 * g);

  f32x4 acc[4] = {};
  float mrow[4] = {-INFINITY, -INFINITY, -INFINITY, -INFINITY};
  float lrow[4] = {0.f, 0.f, 0.f, 0.f};

  const int ntiles = (q0 + 15) / 64 + 1;
  for (int kt = 0; kt < ntiles; ++kt) {
    const int k0 = kt * 64;
    // S = Q K^T for 64 keys: 4 col-blocks x 2 dh-chunks
    f32x4 s[4];
#pragma unroll
    for (int j = 0; j < 4; ++j) {
      const f16* kr = Kb + (size_t)(k0 + 16 * j + lr) * 64 + 8 * g;
      const half8 ka = *(const half8*)kr;
      const half8 kb2 = *(const half8*)(kr + 32);
      f32x4 z = {};
      z = __builtin_amdgcn_mfma_f32_16x16x32_f16(qf0, ka, z, 0, 0, 0);
      s[j] = __builtin_amdgcn_mfma_f32_16x16x32_f16(qf1, kb2, z, 0, 0, 0);
    }
    if (k0 + 63 > q0) {  // tile touches/crosses the diagonal
#pragma unroll
      for (int j = 0; j < 4; ++j) {
        const int key = k0 + 16 * j + lr;
#pragma unroll
        for (int r = 0; r < 4; ++r)
          if (key > q0 + 4 * g + r) s[j][r] = -INFINITY;
      }
    }
    // online softmax per row (rows live across the 16 lanes sharing g)
#pragma unroll
    for (int r = 0; r < 4; ++r) {
      float t = fmaxf(fmaxf(s[0][r], s[1][r]), fmaxf(s[2][r], s[3][r]));
      t = fmaxf(t, __shfl_xor(t, 1));
      t = fmaxf(t, __shfl_xor(t, 2));
      t = fmaxf(t, __shfl_xor(t, 4));
      t = fmaxf(t, __shfl_xor(t, 8));
      const float mn = fmaxf(mrow[r], t);
      const float sf = __expf(mrow[r] - mn);
      mrow[r] = mn;
      float rs = 0.f;
#pragma unroll
      for (int j = 0; j < 4; ++j) {
        const float pv = __expf(s[j][r] - mn);
        s[j][r] = pv;
        rs += pv;
      }
      rs += __shfl_xor(rs, 1);
      rs += __shfl_xor(rs, 2);
      rs += __shfl_xor(rs, 4);
      rs += __shfl_xor(rs, 8);
      lrow[r] = lrow[r] * sf + rs;
#pragma unroll
      for (int nb = 0; nb < 4; ++nb) acc[nb][r] *= sf;
    }
    // transpose P (D-layout) -> A-layout via wave-private LDS
#pragma unroll
    for (int j = 0; j < 4; ++j)
#pragma unroll
      for (int r = 0; r < 4; ++r)
        plds[4 * g + r][16 * j + lr] = (f16)s[j][r];
    asm volatile("s_waitcnt lgkmcnt(0)" ::: "memory");
    __builtin_amdgcn_sched_barrier(0);
    const half8 pf0 = *(const half8*)(&plds[lr][8 * g]);
    const half8 pf1 = *(const half8*)(&plds[lr][32 + 8 * g]);
#pragma unroll
    for (int nb = 0; nb < 4; ++nb) {
      const f16* vr = Vb + (size_t)(16 * nb + lr) * 2048 + k0 + 8 * g;
      const half8 va = *(const half8*)vr;
      const half8 vb2 = *(const half8*)(vr + 32);
      acc[nb] = __builtin_amdgcn_mfma_f32_16x16x32_f16(pf0, va, acc[nb], 0, 0, 0);
      acc[nb] = __builtin_amdgcn_mfma_f32_16x16x32_f16(pf1, vb2, acc[nb], 0, 0, 0);
    }
    __builtin_amdgcn_sched_barrier(0);  // keep P reads ahead of next tile's writes
  }

  const int b = bh >> 4, h = bh & 15;
#pragma unroll
  for (int r = 0; r < 4; ++r) {
    const float inv = 1.f / lrow[r];
    const int q = q0 + 4 * g + r;
    f16* orow = O + ((size_t)(b * 2048 + q) * 1024) + h * 64;
#pragma unroll
    for (int nb = 0; nb < 4; ++nb) orow[16 * nb + lr] = (f16)(acc[nb][r] * inv);
  }
}

extern "C" void kernel_launch(void* const* d_in, const int* in_sizes, int n_in,
                              void* d_out, int out_size, void* d_ws, size_t ws_size,
                              hipStream_t stream) {
  const float* x = (const float*)d_in[0];     // [2][2048][1024]
  const float* Wqkv = (const float*)d_in[1];  // [1024][3072]
  const float* Wout = (const float*)d_in[2];  // [1024][1024]

  char* p = (char*)d_ws;
  f16* Xb = (f16*)p;    p += (size_t)4096 * 1024 * 2;      // x in f16
  f16* Wqkvt = (f16*)p; p += (size_t)3072 * 1024 * 2;      // W_qkv^T f16
  f16* Woutt = (f16*)p; p += (size_t)1024 * 1024 * 2;      // W_out^T f16
  f16* Qp = (f16*)p;    p += (size_t)32 * 2048 * 64 * 2;   // [b*h][n][d], pre-scaled
  f16* Kp = (f16*)p;    p += (size_t)32 * 2048 * 64 * 2;   // [b*h][n][d]
  f16* Vt = (f16*)p;    p += (size_t)32 * 64 * 2048 * 2;   // [b*h][d][n]
  f16* O = (f16*)p;     p += (size_t)4096 * 1024 * 2;      // [b*n][h*64+d]

  k_cvt<<<4096, 256, 0, stream>>>((const float4*)x, (f16x4*)Xb, 4096 * 1024 / 4);
  k_transpose<<<dim3(96, 32), dim3(32, 8), 0, stream>>>(Wqkv, Wqkvt, 1024, 3072);
  k_transpose<<<dim3(32, 32), dim3(32, 8), 0, stream>>>(Wout, Woutt, 1024, 1024);
  k_gemm<0><<<dim3(24, 32), 256, 0, stream>>>(Xb, Wqkvt, nullptr, Qp, Kp, Vt);
  k_attn<<<1024, 256, 0, stream>>>(Qp, Kp, Vt, O);
  k_gemm<1><<<dim3(8, 32), 256, 0, stream>>>(O, Woutt, (float*)d_out, nullptr, nullptr, nullptr);
}

// Round 2
// 272.795 us; speedup vs baseline: 1.5667x; 1.5667x over previous
//
#include <hip/hip_runtime.h>

typedef _Float16 f16;
typedef f16 half8 __attribute__((ext_vector_type(8)));
typedef f16 f16x4 __attribute__((ext_vector_type(4)));
typedef float f32x4 __attribute__((ext_vector_type(4)));

#define GLOAD_LDS16(gsrc, ldst)                                                              \
  __builtin_amdgcn_global_load_lds((const __attribute__((address_space(1))) void*)(gsrc),    \
                                   (__attribute__((address_space(3))) void*)(ldst), 16, 0, 0)

constexpr float SCALE = 0.125f;  // 64^-0.5

// ---------------- convert f32 -> f16, vectorized x4 ----------------
__global__ __launch_bounds__(256) void k_cvt(const float4* __restrict__ in,
                                             f16x4* __restrict__ out, int n4) {
  int i = blockIdx.x * 256 + threadIdx.x;
  if (i < n4) {
    float4 v = in[i];
    f16x4 o;
    o[0] = (f16)v.x; o[1] = (f16)v.y; o[2] = (f16)v.z; o[3] = (f16)v.w;
    out[i] = o;
  }
}

// ---------------- transpose f32 [R][C] -> f16 [C][R] ----------------
__global__ __launch_bounds__(256) void k_transpose(const float* __restrict__ in,
                                                   f16* __restrict__ out, int R, int C) {
  __shared__ float t[32][33];
  int c0 = blockIdx.x * 32, r0 = blockIdx.y * 32;
  int tx = threadIdx.x, ty = threadIdx.y;
  for (int i = ty; i < 32; i += 8) t[i][tx] = in[(size_t)(r0 + i) * C + c0 + tx];
  __syncthreads();
  for (int i = ty; i < 32; i += 8) out[(size_t)(c0 + i) * R + r0 + tx] = (f16)t[tx][i];
}

// ---------------- GEMM: C[M][N] = A[M][1024] * Bt[N][1024]^T ----------------
// (unchanged from round 1 — verified correct; m97-style 128x128/BK=64 structure)
template <int MODE>
__global__ __launch_bounds__(256) void k_gemm(const f16* __restrict__ A,
                                              const f16* __restrict__ Bt,
                                              float* __restrict__ C,
                                              f16* __restrict__ Qp,
                                              f16* __restrict__ Kp,
                                              f16* __restrict__ Vt) {
  constexpr int K = 1024, BK = 64;
  __shared__ alignas(16) f16 As[128 * BK];
  __shared__ alignas(16) f16 Bs[128 * BK];
  const int tid = threadIdx.x;
  const int w = tid >> 6, lane = tid & 63;
  const int g = lane >> 4, lr = lane & 15;
  const int wr = w >> 1, wc = w & 1;
  const int m0 = blockIdx.y * 128, n0 = blockIdx.x * 128;
  const int srow = lane >> 3;                 // row within 8-row chunk
  const int scol = ((lane & 7) ^ srow) << 3;  // swizzled half offset within 64-half row

  f32x4 acc[4][4] = {};

  for (int kt = 0; kt < K; kt += BK) {
    __syncthreads();
#pragma unroll
    for (int i = 0; i < 4; ++i) {
      const int chunk = w * 4 + i;
      const int row = chunk * 8 + srow;
      GLOAD_LDS16(A + (size_t)(m0 + row) * K + kt + scol, &As[chunk * 512]);
      GLOAD_LDS16(Bt + (size_t)(n0 + row) * K + kt + scol, &Bs[chunk * 512]);
    }
    __syncthreads();
#pragma unroll
    for (int c = 0; c < 2; ++c) {
      half8 af[4], bf[4];
#pragma unroll
      for (int m = 0; m < 4; ++m) {
        const int ra = wr * 64 + m * 16 + lr;
        const int off = ra * 128 + ((((c << 2) | g) ^ (ra & 7)) << 4);
        af[m] = *(const half8*)((const char*)As + off);
      }
#pragma unroll
      for (int n = 0; n < 4; ++n) {
        const int rb = wc * 64 + n * 16 + lr;
        const int off = rb * 128 + ((((c << 2) | g) ^ (rb & 7)) << 4);
        bf[n] = *(const half8*)((const char*)Bs + off);
      }
#pragma unroll
      for (int m = 0; m < 4; ++m)
#pragma unroll
        for (int n = 0; n < 4; ++n)
          acc[m][n] = __builtin_amdgcn_mfma_f32_16x16x32_f16(af[m], bf[n], acc[m][n], 0, 0, 0);
    }
  }

  if constexpr (MODE == 0) {
#pragma unroll
    for (int m = 0; m < 4; ++m) {
      const int trow = m0 + wr * 64 + m * 16 + 4 * g;
#pragma unroll
      for (int n = 0; n < 4; ++n) {
        const int e = n0 + wc * 64 + n * 16 + lr;  // e = d*48 + wh*16 + h
        const int d = e / 48;
        const int rem = e - d * 48;
        const int wh = rem >> 4, h = rem & 15;
#pragma unroll
        for (int r = 0; r < 4; ++r) {
          const int tok = trow + r;
          const int bh = ((tok >> 11) << 4) + h;
          const int nn = tok & 2047;
          const float v = acc[m][n][r];
          if (wh == 0)
            Qp[((size_t)bh * 2048 + nn) * 64 + d] = (f16)(v * SCALE);
          else if (wh == 1)
            Kp[((size_t)bh * 2048 + nn) * 64 + d] = (f16)v;
          else
            Vt[((size_t)bh * 64 + d) * 2048 + nn] = (f16)v;
        }
      }
    }
  } else {
#pragma unroll
    for (int m = 0; m < 4; ++m)
#pragma unroll
      for (int n = 0; n < 4; ++n)
#pragma unroll
        for (int r = 0; r < 4; ++r)
          C[(size_t)(m0 + wr * 64 + m * 16 + 4 * g + r) * 1024 +
            (n0 + wc * 64 + n * 16 + lr)] = acc[m][n][r];
  }
}

// ---------------- causal flash attention v2 ----------------
// 4 independent waves/block (no barriers), 32 q-rows/wave via 2x 16-row frags.
// 1-deep K register prefetch; V issued at tile top (latency hides under softmax).
// Complementary q-tile encoding balances causal work across co-resident blocks.
__global__ __launch_bounds__(256, 2) void k_attn(const f16* __restrict__ Q,
                                                 const f16* __restrict__ Kp,
                                                 const f16* __restrict__ Vt,
                                                 f16* __restrict__ O) {
  __shared__ alignas(16) f16 plds_all[4][2][16][72];
  const int tid = threadIdx.x;
  const int w = tid >> 6, lane = tid & 63;
  const int g = lane >> 4, lr = lane & 15;
  const int bh = blockIdx.x & 31;
  const int u = blockIdx.x >> 5;       // 0..15
  const int t = (u < 8) ? u : 23 - u;  // pair t with 15-t across dispatch stride 256
  const int q0 = t * 128 + w * 32;     // wave's 32 rows: q0 + 16f + lr
  f16(*plds)[16][72] = plds_all[w];

  const f16* __restrict__ Qb = Q + (size_t)bh * (2048 * 64);
  const f16* __restrict__ Kb = Kp + (size_t)bh * (2048 * 64);
  const f16* __restrict__ Vb = Vt + (size_t)bh * (64 * 2048);

  // Q fragments: A-layout row = lane&15, k = 8*(lane>>4)+i
  half8 qf[2][2];
#pragma unroll
  for (int f = 0; f < 2; ++f)
#pragma unroll
    for (int c = 0; c < 2; ++c)
      qf[f][c] = *(const half8*)(Qb + (size_t)(q0 + 16 * f + lr) * 64 + 32 * c + 8 * g);

  f32x4 acc[2][4] = {};
  float mrow[2][4], lrow[2][4];
#pragma unroll
  for (int f = 0; f < 2; ++f)
#pragma unroll
    for (int r = 0; r < 4; ++r) {
      mrow[f][r] = -INFINITY;
      lrow[f][r] = 0.f;
    }

  const int ntiles = (q0 + 31) / 64 + 1;

  // preload K tile 0 into registers
  half8 kc[4][2], kn[4][2];
#pragma unroll
  for (int j = 0; j < 4; ++j)
#pragma unroll
    for (int c = 0; c < 2; ++c)
      kc[j][c] = *(const half8*)(Kb + (size_t)(16 * j + lr) * 64 + 32 * c + 8 * g);

  for (int kt = 0; kt < ntiles; ++kt) {
    const int k0 = kt * 64;
    // ---- issue V loads for this tile (consumed after softmax) ----
    half8 va[4][2];
#pragma unroll
    for (int nb = 0; nb < 4; ++nb)
#pragma unroll
      for (int c = 0; c < 2; ++c)
        va[nb][c] = *(const half8*)(Vb + (size_t)(16 * nb + lr) * 2048 + k0 + 32 * c + 8 * g);
    // ---- issue K loads for next tile (consumed next iteration) ----
    const int knext = (kt + 1 < ntiles ? kt + 1 : kt) * 64;
#pragma unroll
    for (int j = 0; j < 4; ++j)
#pragma unroll
      for (int c = 0; c < 2; ++c)
        kn[j][c] = *(const half8*)(Kb + (size_t)(knext + 16 * j + lr) * 64 + 32 * c + 8 * g);

    // ---- S = Q K^T (uses resident kc) ----
    f32x4 s[2][4];
#pragma unroll
    for (int f = 0; f < 2; ++f)
#pragma unroll
      for (int j = 0; j < 4; ++j) {
        f32x4 z = {};
        z = __builtin_amdgcn_mfma_f32_16x16x32_f16(qf[f][0], kc[j][0], z, 0, 0, 0);
        s[f][j] = __builtin_amdgcn_mfma_f32_16x16x32_f16(qf[f][1], kc[j][1], z, 0, 0, 0);
      }

    if (k0 + 63 > q0) {  // tile touches/crosses the diagonal
#pragma unroll
      for (int f = 0; f < 2; ++f)
#pragma unroll
        for (int j = 0; j < 4; ++j) {
          const int key = k0 + 16 * j + lr;
#pragma unroll
          for (int r = 0; r < 4; ++r)
            if (key > q0 + 16 * f + 4 * g + r) s[f][j][r] = -INFINITY;
        }
    }

    // ---- online softmax (rows live across the 16 lanes sharing g) ----
#pragma unroll
    for (int f = 0; f < 2; ++f)
#pragma unroll
      for (int r = 0; r < 4; ++r) {
        float tmax = fmaxf(fmaxf(s[f][0][r], s[f][1][r]), fmaxf(s[f][2][r], s[f][3][r]));
        tmax = fmaxf(tmax, __shfl_xor(tmax, 1));
        tmax = fmaxf(tmax, __shfl_xor(tmax, 2));
        tmax = fmaxf(tmax, __shfl_xor(tmax, 4));
        tmax = fmaxf(tmax, __shfl_xor(tmax, 8));
        const float mn = fmaxf(mrow[f][r], tmax);
        const float sf = __expf(mrow[f][r] - mn);
        mrow[f][r] = mn;
        float rs = 0.f;
#pragma unroll
        for (int j = 0; j < 4; ++j) {
          const float pv = __expf(s[f][j][r] - mn);
          s[f][j][r] = pv;
          rs += pv;
        }
        rs += __shfl_xor(rs, 1);
        rs += __shfl_xor(rs, 2);
        rs += __shfl_xor(rs, 4);
        rs += __shfl_xor(rs, 8);
        lrow[f][r] = lrow[f][r] * sf + rs;
#pragma unroll
        for (int nb = 0; nb < 4; ++nb) acc[f][nb][r] *= sf;
      }

    // ---- transpose P (D-layout) -> A-layout via wave-private LDS ----
#pragma unroll
    for (int f = 0; f < 2; ++f)
#pragma unroll
      for (int j = 0; j < 4; ++j)
#pragma unroll
        for (int r = 0; r < 4; ++r)
          plds[f][4 * g + r][16 * j + lr] = (f16)s[f][j][r];
    asm volatile("s_waitcnt lgkmcnt(0)" ::: "memory");
    __builtin_amdgcn_sched_barrier(0);
    half8 pf[2][2];
#pragma unroll
    for (int f = 0; f < 2; ++f)
#pragma unroll
      for (int c = 0; c < 2; ++c)
        pf[f][c] = *(const half8*)(&plds[f][lr][32 * c + 8 * g]);

    // ---- PV (V latency hidden under softmax) ----
#pragma unroll
    for (int f = 0; f < 2; ++f)
#pragma unroll
      for (int nb = 0; nb < 4; ++nb) {
        acc[f][nb] = __builtin_amdgcn_mfma_f32_16x16x32_f16(pf[f][0], va[nb][0], acc[f][nb], 0, 0, 0);
        acc[f][nb] = __builtin_amdgcn_mfma_f32_16x16x32_f16(pf[f][1], va[nb][1], acc[f][nb], 0, 0, 0);
      }
    __builtin_amdgcn_sched_barrier(0);  // keep P reads ahead of next tile's writes

    // rotate K prefetch
#pragma unroll
    for (int j = 0; j < 4; ++j)
#pragma unroll
      for (int c = 0; c < 2; ++c)
        kc[j][c] = kn[j][c];
  }

  const int b = bh >> 4, h = bh & 15;
#pragma unroll
  for (int f = 0; f < 2; ++f)
#pragma unroll
    for (int r = 0; r < 4; ++r) {
      const float inv = 1.f / lrow[f][r];
      const int q = q0 + 16 * f + 4 * g + r;
      f16* orow = O + ((size_t)(b * 2048 + q) * 1024) + h * 64;
#pragma unroll
      for (int nb = 0; nb < 4; ++nb) orow[16 * nb + lr] = (f16)(acc[f][nb][r] * inv);
    }
}

extern "C" void kernel_launch(void* const* d_in, const int* in_sizes, int n_in,
                              void* d_out, int out_size, void* d_ws, size_t ws_size,
                              hipStream_t stream) {
  const float* x = (const float*)d_in[0];     // [2][2048][1024]
  const float* Wqkv = (const float*)d_in[1];  // [1024][3072]
  const float* Wout = (const float*)d_in[2];  // [1024][1024]

  char* p = (char*)d_ws;
  f16* Xb = (f16*)p;    p += (size_t)4096 * 1024 * 2;      // x in f16
  f16* Wqkvt = (f16*)p; p += (size_t)3072 * 1024 * 2;      // W_qkv^T f16
  f16* Woutt = (f16*)p; p += (size_t)1024 * 1024 * 2;      // W_out^T f16
  f16* Qp = (f16*)p;    p += (size_t)32 * 2048 * 64 * 2;   // [b*h][n][d], pre-scaled
  f16* Kp = (f16*)p;    p += (size_t)32 * 2048 * 64 * 2;   // [b*h][n][d]
  f16* Vt = (f16*)p;    p += (size_t)32 * 64 * 2048 * 2;   // [b*h][d][n]
  f16* O = (f16*)p;     p += (size_t)4096 * 1024 * 2;      // [b*n][h*64+d]

  k_cvt<<<4096, 256, 0, stream>>>((const float4*)x, (f16x4*)Xb, 4096 * 1024 / 4);
  k_transpose<<<dim3(96, 32), dim3(32, 8), 0, stream>>>(Wqkv, Wqkvt, 1024, 3072);
  k_transpose<<<dim3(32, 32), dim3(32, 8), 0, stream>>>(Wout, Woutt, 1024, 1024);
  k_gemm<0><<<dim3(24, 32), 256, 0, stream>>>(Xb, Wqkvt, nullptr, Qp, Kp, Vt);
  k_attn<<<512, 256, 0, stream>>>(Qp, Kp, Vt, O);
  k_gemm<1><<<dim3(8, 32), 256, 0, stream>>>(O, Woutt, (float*)d_out, nullptr, nullptr, nullptr);
}

// Round 3
// 221.783 us; speedup vs baseline: 1.9271x; 1.2300x over previous
//
#include <hip/hip_runtime.h>

typedef _Float16 f16;
typedef f16 half8 __attribute__((ext_vector_type(8)));
typedef f16 f16x4 __attribute__((ext_vector_type(4)));
typedef float f32x4 __attribute__((ext_vector_type(4)));

#define GLOAD_LDS16(gsrc, ldst)                                                              \
  __builtin_amdgcn_global_load_lds((const __attribute__((address_space(1))) void*)(gsrc),    \
                                   (__attribute__((address_space(3))) void*)(ldst), 16, 0, 0)

constexpr float SCALE = 0.125f;  // 64^-0.5

// ---------------- convert f32 -> f16, vectorized x4 ----------------
__global__ __launch_bounds__(256) void k_cvt(const float4* __restrict__ in,
                                             f16x4* __restrict__ out, int n4) {
  int i = blockIdx.x * 256 + threadIdx.x;
  if (i < n4) {
    float4 v = in[i];
    f16x4 o;
    o[0] = (f16)v.x; o[1] = (f16)v.y; o[2] = (f16)v.z; o[3] = (f16)v.w;
    out[i] = o;
  }
}

// ---------------- transpose f32 [R][C] -> f16 [C][R] (generic, for W_out) ----
__global__ __launch_bounds__(256) void k_transpose(const float* __restrict__ in,
                                                   f16* __restrict__ out, int R, int C) {
  __shared__ float t[32][33];
  int c0 = blockIdx.x * 32, r0 = blockIdx.y * 32;
  int tx = threadIdx.x, ty = threadIdx.y;
  for (int i = ty; i < 32; i += 8) t[i][tx] = in[(size_t)(r0 + i) * C + c0 + tx];
  __syncthreads();
  for (int i = ty; i < 32; i += 8) out[(size_t)(c0 + i) * R + r0 + tx] = (f16)t[tx][i];
}

// -------- W_qkv transpose with column-permuted output row order ----------
// in: [1024][3072], col e = d*48 + k*16 + h (reference's (dh,3,h) factorization).
// out row e' = k*1024 + h*64 + d  ->  GEMM N-dim becomes [which][head][d]-ordered,
// so the QKV epilogue stores are d-contiguous (kills the 8x write amplification).
__global__ __launch_bounds__(256) void k_transpose_qkv(const float* __restrict__ in,
                                                       f16* __restrict__ out) {
  __shared__ float t[32][33];
  int c0 = blockIdx.x * 32, r0 = blockIdx.y * 32;
  int tx = threadIdx.x, ty = threadIdx.y;
  for (int i = ty; i < 32; i += 8) t[i][tx] = in[(size_t)(r0 + i) * 3072 + c0 + tx];
  __syncthreads();
  for (int i = ty; i < 32; i += 8) {
    const int e = c0 + i;
    const int d = e / 48, rem = e - d * 48;
    const int k = rem >> 4, h = rem & 15;
    const int ep = k * 1024 + h * 64 + d;
    out[(size_t)ep * 1024 + r0 + tx] = (f16)t[tx][i];
  }
}

// ---------------- GEMM: C[M][N] = A[M][1024] * Bt[N][1024]^T ----------------
// 128x128 tile, BK=64, 4 waves (2x2), m97-style global_load_lds staging.
// MODE 0 (QKV, permuted N): sec = n0>>10 selects Q/K/V uniformly per block.
//   Q/K: direct d-contiguous stores. V: 128x128 LDS transpose (XOR-swizzled,
//   reusing the staging LDS) -> 16B token-contiguous stores into Vt[bh][d][n].
// MODE 1: plain fp32 store (N=1024).
template <int MODE>
__global__ __launch_bounds__(256) void k_gemm(const f16* __restrict__ A,
                                              const f16* __restrict__ Bt,
                                              float* __restrict__ C,
                                              f16* __restrict__ Qp,
                                              f16* __restrict__ Kp,
                                              f16* __restrict__ Vt) {
  constexpr int K = 1024, BK = 64;
  __shared__ alignas(16) f16 smem[128 * 128];  // As | Bs during K-loop; V scratch in epilogue
  f16* As = smem;
  f16* Bs = smem + 128 * 64;
  const int tid = threadIdx.x;
  const int w = tid >> 6, lane = tid & 63;
  const int g = lane >> 4, lr = lane & 15;
  const int wr = w >> 1, wc = w & 1;
  const int m0 = blockIdx.y * 128, n0 = blockIdx.x * 128;
  const int srow = lane >> 3;                 // row within 8-row chunk
  const int scol = ((lane & 7) ^ srow) << 3;  // swizzled half offset within 64-half row

  f32x4 acc[4][4] = {};

  for (int kt = 0; kt < K; kt += BK) {
    __syncthreads();
#pragma unroll
    for (int i = 0; i < 4; ++i) {
      const int chunk = w * 4 + i;
      const int row = chunk * 8 + srow;
      GLOAD_LDS16(A + (size_t)(m0 + row) * K + kt + scol, &As[chunk * 512]);
      GLOAD_LDS16(Bt + (size_t)(n0 + row) * K + kt + scol, &Bs[chunk * 512]);
    }
    __syncthreads();
#pragma unroll
    for (int c = 0; c < 2; ++c) {
      half8 af[4], bf[4];
#pragma unroll
      for (int m = 0; m < 4; ++m) {
        const int ra = wr * 64 + m * 16 + lr;
        const int off = ra * 128 + ((((c << 2) | g) ^ (ra & 7)) << 4);
        af[m] = *(const half8*)((const char*)As + off);
      }
#pragma unroll
      for (int n = 0; n < 4; ++n) {
        const int rb = wc * 64 + n * 16 + lr;
        const int off = rb * 128 + ((((c << 2) | g) ^ (rb & 7)) << 4);
        bf[n] = *(const half8*)((const char*)Bs + off);
      }
#pragma unroll
      for (int m = 0; m < 4; ++m)
#pragma unroll
        for (int n = 0; n < 4; ++n)
          acc[m][n] = __builtin_amdgcn_mfma_f32_16x16x32_f16(af[m], bf[n], acc[m][n], 0, 0, 0);
    }
  }

  // D layout (m89-verified): col = lane&15, row = 4*(lane>>4) + reg
  if constexpr (MODE == 0) {
    const int sec = n0 >> 10;    // 0=Q, 1=K, 2=V (uniform per block)
    const int base = n0 & 1023;  // within-section column base
    const int b = m0 >> 11;      // batch (uniform: 128 | 2048)
    if (sec < 2) {
      f16* __restrict__ dst = (sec == 0) ? Qp : Kp;
      const float mul = (sec == 0) ? SCALE : 1.0f;
#pragma unroll
      for (int n = 0; n < 4; ++n) {
        const int idx = base + wc * 64 + n * 16 + lr;
        const int h = idx >> 6, d = idx & 63;
        f16* __restrict__ dh = dst + ((size_t)(b * 16 + h) * 2048) * 64 + d;
#pragma unroll
        for (int m = 0; m < 4; ++m)
#pragma unroll
          for (int r = 0; r < 4; ++r) {
            const int nn = (m0 & 2047) + wr * 64 + m * 16 + 4 * g + r;
            dh[(size_t)nn * 64] = (f16)(acc[m][n][r] * mul);
          }
      }
    } else {
      // V: transpose the 128x128 tile via swizzled LDS, store token-contiguous.
      char* sb = (char*)smem;
      __syncthreads();  // staging reads done; reuse LDS
#pragma unroll
      for (int m = 0; m < 4; ++m)
#pragma unroll
        for (int n = 0; n < 4; ++n) {
          const int col = wc * 64 + n * 16 + lr;
          const int tok0 = wr * 64 + m * 16 + 4 * g;  // multiple of 4
          f16x4 v4;
#pragma unroll
          for (int r = 0; r < 4; ++r) v4[r] = (f16)acc[m][n][r];
          *(f16x4*)(sb + col * 256 + ((tok0 * 2) ^ ((col & 15) << 4))) = v4;
        }
      __syncthreads();
      const int nn0 = m0 & 2047;
#pragma unroll
      for (int pass = 0; pass < 8; ++pass) {
        const int c = w * 32 + pass * 4 + g;  // tile column = V output row
        const int idx = base + c;
        const int h = idx >> 6, d = idx & 63;
        const half8 v = *(const half8*)(sb + c * 256 + ((lr * 16) ^ ((c & 15) << 4)));
        *(half8*)(Vt + ((size_t)(b * 16 + h) * 64 + d) * 2048 + nn0 + lr * 8) = v;
      }
    }
  } else {
#pragma unroll
    for (int m = 0; m < 4; ++m)
#pragma unroll
      for (int n = 0; n < 4; ++n)
#pragma unroll
        for (int r = 0; r < 4; ++r)
          C[(size_t)(m0 + wr * 64 + m * 16 + 4 * g + r) * 1024 +
            (n0 + wc * 64 + n * 16 + lr)] = acc[m][n][r];
  }
}

// ---------------- causal flash attention v2 (unchanged from round 2) ----------
__global__ __launch_bounds__(256, 2) void k_attn(const f16* __restrict__ Q,
                                                 const f16* __restrict__ Kp,
                                                 const f16* __restrict__ Vt,
                                                 f16* __restrict__ O) {
  __shared__ alignas(16) f16 plds_all[4][2][16][72];
  const int tid = threadIdx.x;
  const int w = tid >> 6, lane = tid & 63;
  const int g = lane >> 4, lr = lane & 15;
  const int bh = blockIdx.x & 31;
  const int u = blockIdx.x >> 5;       // 0..15
  const int t = (u < 8) ? u : 23 - u;  // complementary causal-load pairing
  const int q0 = t * 128 + w * 32;
  f16(*plds)[16][72] = plds_all[w];

  const f16* __restrict__ Qb = Q + (size_t)bh * (2048 * 64);
  const f16* __restrict__ Kb = Kp + (size_t)bh * (2048 * 64);
  const f16* __restrict__ Vb = Vt + (size_t)bh * (64 * 2048);

  half8 qf[2][2];
#pragma unroll
  for (int f = 0; f < 2; ++f)
#pragma unroll
    for (int c = 0; c < 2; ++c)
      qf[f][c] = *(const half8*)(Qb + (size_t)(q0 + 16 * f + lr) * 64 + 32 * c + 8 * g);

  f32x4 acc[2][4] = {};
  float mrow[2][4], lrow[2][4];
#pragma unroll
  for (int f = 0; f < 2; ++f)
#pragma unroll
    for (int r = 0; r < 4; ++r) {
      mrow[f][r] = -INFINITY;
      lrow[f][r] = 0.f;
    }

  const int ntiles = (q0 + 31) / 64 + 1;

  half8 kc[4][2], kn[4][2];
#pragma unroll
  for (int j = 0; j < 4; ++j)
#pragma unroll
    for (int c = 0; c < 2; ++c)
      kc[j][c] = *(const half8*)(Kb + (size_t)(16 * j + lr) * 64 + 32 * c + 8 * g);

  for (int kt = 0; kt < ntiles; ++kt) {
    const int k0 = kt * 64;
    half8 va[4][2];
#pragma unroll
    for (int nb = 0; nb < 4; ++nb)
#pragma unroll
      for (int c = 0; c < 2; ++c)
        va[nb][c] = *(const half8*)(Vb + (size_t)(16 * nb + lr) * 2048 + k0 + 32 * c + 8 * g);
    const int knext = (kt + 1 < ntiles ? kt + 1 : kt) * 64;
#pragma unroll
    for (int j = 0; j < 4; ++j)
#pragma unroll
      for (int c = 0; c < 2; ++c)
        kn[j][c] = *(const half8*)(Kb + (size_t)(knext + 16 * j + lr) * 64 + 32 * c + 8 * g);

    f32x4 s[2][4];
#pragma unroll
    for (int f = 0; f < 2; ++f)
#pragma unroll
      for (int j = 0; j < 4; ++j) {
        f32x4 z = {};
        z = __builtin_amdgcn_mfma_f32_16x16x32_f16(qf[f][0], kc[j][0], z, 0, 0, 0);
        s[f][j] = __builtin_amdgcn_mfma_f32_16x16x32_f16(qf[f][1], kc[j][1], z, 0, 0, 0);
      }

    if (k0 + 63 > q0) {
#pragma unroll
      for (int f = 0; f < 2; ++f)
#pragma unroll
        for (int j = 0; j < 4; ++j) {
          const int key = k0 + 16 * j + lr;
#pragma unroll
          for (int r = 0; r < 4; ++r)
            if (key > q0 + 16 * f + 4 * g + r) s[f][j][r] = -INFINITY;
        }
    }

#pragma unroll
    for (int f = 0; f < 2; ++f)
#pragma unroll
      for (int r = 0; r < 4; ++r) {
        float tmax = fmaxf(fmaxf(s[f][0][r], s[f][1][r]), fmaxf(s[f][2][r], s[f][3][r]));
        tmax = fmaxf(tmax, __shfl_xor(tmax, 1));
        tmax = fmaxf(tmax, __shfl_xor(tmax, 2));
        tmax = fmaxf(tmax, __shfl_xor(tmax, 4));
        tmax = fmaxf(tmax, __shfl_xor(tmax, 8));
        const float mn = fmaxf(mrow[f][r], tmax);
        const float sf = __expf(mrow[f][r] - mn);
        mrow[f][r] = mn;
        float rs = 0.f;
#pragma unroll
        for (int j = 0; j < 4; ++j) {
          const float pv = __expf(s[f][j][r] - mn);
          s[f][j][r] = pv;
          rs += pv;
        }
        rs += __shfl_xor(rs, 1);
        rs += __shfl_xor(rs, 2);
        rs += __shfl_xor(rs, 4);
        rs += __shfl_xor(rs, 8);
        lrow[f][r] = lrow[f][r] * sf + rs;
#pragma unroll
        for (int nb = 0; nb < 4; ++nb) acc[f][nb][r] *= sf;
      }

#pragma unroll
    for (int f = 0; f < 2; ++f)
#pragma unroll
      for (int j = 0; j < 4; ++j)
#pragma unroll
        for (int r = 0; r < 4; ++r)
          plds[f][4 * g + r][16 * j + lr] = (f16)s[f][j][r];
    asm volatile("s_waitcnt lgkmcnt(0)" ::: "memory");
    __builtin_amdgcn_sched_barrier(0);
    half8 pf[2][2];
#pragma unroll
    for (int f = 0; f < 2; ++f)
#pragma unroll
      for (int c = 0; c < 2; ++c)
        pf[f][c] = *(const half8*)(&plds[f][lr][32 * c + 8 * g]);

#pragma unroll
    for (int f = 0; f < 2; ++f)
#pragma unroll
      for (int nb = 0; nb < 4; ++nb) {
        acc[f][nb] = __builtin_amdgcn_mfma_f32_16x16x32_f16(pf[f][0], va[nb][0], acc[f][nb], 0, 0, 0);
        acc[f][nb] = __builtin_amdgcn_mfma_f32_16x16x32_f16(pf[f][1], va[nb][1], acc[f][nb], 0, 0, 0);
      }
    __builtin_amdgcn_sched_barrier(0);

#pragma unroll
    for (int j = 0; j < 4; ++j)
#pragma unroll
      for (int c = 0; c < 2; ++c)
        kc[j][c] = kn[j][c];
  }

  const int b = bh >> 4, h = bh & 15;
#pragma unroll
  for (int f = 0; f < 2; ++f)
#pragma unroll
    for (int r = 0; r < 4; ++r) {
      const float inv = 1.f / lrow[f][r];
      const int q = q0 + 16 * f + 4 * g + r;
      f16* orow = O + ((size_t)(b * 2048 + q) * 1024) + h * 64;
#pragma unroll
      for (int nb = 0; nb < 4; ++nb) orow[16 * nb + lr] = (f16)(acc[f][nb][r] * inv);
    }
}

extern "C" void kernel_launch(void* const* d_in, const int* in_sizes, int n_in,
                              void* d_out, int out_size, void* d_ws, size_t ws_size,
                              hipStream_t stream) {
  const float* x = (const float*)d_in[0];     // [2][2048][1024]
  const float* Wqkv = (const float*)d_in[1];  // [1024][3072]
  const float* Wout = (const float*)d_in[2];  // [1024][1024]

  char* p = (char*)d_ws;
  f16* Xb = (f16*)p;    p += (size_t)4096 * 1024 * 2;      // x in f16
  f16* Wqkvt = (f16*)p; p += (size_t)3072 * 1024 * 2;      // W_qkv^T f16, rows e'=[k][h][d]
  f16* Woutt = (f16*)p; p += (size_t)1024 * 1024 * 2;      // W_out^T f16
  f16* Qp = (f16*)p;    p += (size_t)32 * 2048 * 64 * 2;   // [b*h][n][d], pre-scaled
  f16* Kp = (f16*)p;    p += (size_t)32 * 2048 * 64 * 2;   // [b*h][n][d]
  f16* Vt = (f16*)p;    p += (size_t)32 * 64 * 2048 * 2;   // [b*h][d][n]
  f16* O = (f16*)p;     p += (size_t)4096 * 1024 * 2;      // [b*n][h*64+d]

  k_cvt<<<4096, 256, 0, stream>>>((const float4*)x, (f16x4*)Xb, 4096 * 1024 / 4);
  k_transpose_qkv<<<dim3(96, 32), dim3(32, 8), 0, stream>>>(Wqkv, Wqkvt);
  k_transpose<<<dim3(32, 32), dim3(32, 8), 0, stream>>>(Wout, Woutt, 1024, 1024);
  k_gemm<0><<<dim3(24, 32), 256, 0, stream>>>(Xb, Wqkvt, nullptr, Qp, Kp, Vt);
  k_attn<<<512, 256, 0, stream>>>(Qp, Kp, Vt, O);
  k_gemm<1><<<dim3(8, 32), 256, 0, stream>>>(O, Woutt, (float*)d_out, nullptr, nullptr, nullptr);
}